// Round 7
// baseline (937.684 us; speedup 1.0000x reference)
//
#include <hip/hip_runtime.h>
#include <math.h>

// ---------------- problem constants ----------------
constexpr int   NN  = 100000;    // nodes
constexpr int   EE  = 1600000;   // edges
constexpr int   HH  = 128;       // hidden / in_channels
constexpr int   GG  = 128;       // graphs
constexpr float EPSV = 1e-5f;
constexpr int   NSH = 8;         // dst shards (level-1 bins)
constexpr int   SHN = NN / NSH;  // 12500 nodes per shard
constexpr int   CAP = 210000;    // per-shard bin capacity (E/8=200k, +5 sigma)
constexpr int   SUBW = (SHN + 31) / 32;  // 391 nodes per sub-bin; 256 sub-bins total

typedef __attribute__((ext_vector_type(8))) short  short8;
typedef __attribute__((ext_vector_type(4))) float  f32x4;
typedef __attribute__((ext_vector_type(2))) float  v2f;

__device__ __forceinline__ unsigned short f2bf(float f) {
    union { float f; unsigned u; } v; v.f = f;
    unsigned r = v.u + 0x7FFF + ((v.u >> 16) & 1);   // round-to-nearest-even
    return (unsigned short)(r >> 16);
}
__device__ __forceinline__ float bf2f(unsigned short b) {
    union { unsigned u; float f; } v; v.u = ((unsigned)b) << 16;
    return v.f;
}

// ---------------- workspace layout ----------------
constexpr size_t A256(size_t x) { return (x + 255) & ~(size_t)255; }
constexpr size_t OFF_TL  = 0;                                       // 8 uints bin tails
constexpr size_t OFF_DEG = A256(OFF_TL  + 8 * 4);                   // N ints (written fully by k_hist)
constexpr size_t OFF_DNV = A256(OFF_DEG + (size_t)NN * 4);          // N floats dinv
constexpr size_t OFF_RP  = A256(OFF_DNV + (size_t)NN * 4);          // (N+1) ints
constexpr size_t OFF_SRC = A256(OFF_RP  + (size_t)(NN + 1) * 4);    // E ints sorted src
constexpr size_t OFF_BIN = A256(OFF_SRC + (size_t)EE * 4);          // 8*CAP uints packed bins
constexpr size_t OFF_BS  = A256(OFF_BIN + (size_t)8 * CAP * 4);     // 512 ints
constexpr size_t OFF_XB  = A256(OFF_BS  + 512 * 4);                 // N*H bf16 (x)
constexpr size_t OFF_HW  = A256(OFF_XB  + (size_t)NN * HH * 2);     // N*H bf16 (h@W)
constexpr size_t OFF_H0  = A256(OFF_HW  + (size_t)NN * HH * 2);     // N*H bf16 (h)
constexpr size_t OFF_PL  = A256(OFF_H0  + (size_t)NN * HH * 2);     // G*H f32 pooled + G f32 cnt

// ---------------- phase A: bin edges by dst-shard, packed 31-bit ----------------
// R6 lesson: FETCH collapsed (bins L2-local) but WRITE amplification stayed 10x
// -> blockIdx&7 is NOT a reliable XCD mapping; every ssrc line was dirtied by
// ~8 non-coherent L2s. R7: write-exclusivity is made STRUCTURAL (one block owns
// each output region) so the XCD mapping becomes irrelevant.
__global__ __launch_bounds__(256) void k_bin(const int* __restrict__ src,
                                             const int* __restrict__ dst,
                                             unsigned* __restrict__ bins,
                                             unsigned* __restrict__ gtail) {
    __shared__ unsigned sbin[8][1024];
    __shared__ unsigned scnt[8];
    __shared__ unsigned sbase[8];
    int t = threadIdx.x;
    if (t < 8) scnt[t] = 0;
    __syncthreads();
    int i = blockIdx.x * 256 + t;            // int4 index
    const int nvec = EE / 4;                 // 400000
    if (i < nvec) {
        int4 d = ((const int4*)dst)[i];
        int4 s = ((const int4*)src)[i];
        int dd[4] = {d.x, d.y, d.z, d.w};
        int ss[4] = {s.x, s.y, s.z, s.w};
#pragma unroll
        for (int c = 0; c < 4; ++c) {
            int sh = dd[c] / SHN;
            unsigned p = atomicAdd(&scnt[sh], 1u);
            sbin[sh][p] = ((unsigned)(dd[c] - sh * SHN) << 17) | (unsigned)ss[c];
        }
    }
    __syncthreads();
    if (t < 8) sbase[t] = atomicAdd(&gtail[t], scnt[t]);
    __syncthreads();
    for (int s = 0; s < 8; ++s) {
        unsigned cnt = scnt[s], base = sbase[s];
        if (base >= (unsigned)CAP) continue;               // safety clamp
        if (base + cnt > (unsigned)CAP) cnt = CAP - base;  // (never in practice)
        for (unsigned j = t; j < cnt; j += 256)
            bins[(size_t)s * CAP + base + j] = sbin[s][j];
    }
}

// ---------------- degree histogram per sub-bin (LDS, zero global atomics) ----------------
// one block owns 391 nodes; streams parent shard bin (L3-served), filters,
// LDS-histograms, writes its deg range exclusively.
__global__ __launch_bounds__(256) void k_hist(const unsigned* __restrict__ bins,
                                              const unsigned* __restrict__ gtail,
                                              int* __restrict__ deg) {
    int b = blockIdx.x;                      // 0..255
    int shard = b >> 5, sub = b & 31;
    int lo = sub * SUBW;
    int hi = lo + SUBW; if (hi > SHN) hi = SHN;
    int nn = hi - lo;
    __shared__ int hist[SUBW];
    for (int i = threadIdx.x; i < nn; i += 256) hist[i] = 0;
    __syncthreads();
    unsigned m = gtail[shard];
    if (m > (unsigned)CAP) m = CAP;
    const unsigned* bb = bins + (size_t)shard * CAP;
    for (unsigned i = threadIdx.x; i < m; i += 256) {
        int dl = (int)(bb[i] >> 17);
        if (dl >= lo && dl < hi) atomicAdd(&hist[dl - lo], 1);
    }
    __syncthreads();
    int gbase = shard * SHN + lo;
    for (int i = threadIdx.x; i < nn; i += 256) deg[gbase + i] = hist[i];
}

__global__ __launch_bounds__(1024) void k_scan_local(const int* __restrict__ deg,
                                                     int* __restrict__ row_ptr,
                                                     int* __restrict__ bsum) {
    __shared__ int s[1024];
    int t = threadIdx.x;
    int i = blockIdx.x * 1024 + t;
    int v = (i < NN) ? deg[i] : 0;
    s[t] = v;
    __syncthreads();
    for (int off = 1; off < 1024; off <<= 1) {
        int u = (t >= off) ? s[t - off] : 0;
        __syncthreads();
        s[t] += u;
        __syncthreads();
    }
    if (i < NN) row_ptr[i] = s[t] - v;
    if (t == 1023) bsum[blockIdx.x] = s[1023];
}

__global__ void k_scan_blocks(int* __restrict__ bsum, int nb) {
    __shared__ int s[128];
    int t = threadIdx.x;
    int v = (t < nb) ? bsum[t] : 0;
    s[t] = v;
    __syncthreads();
    for (int off = 1; off < 128; off <<= 1) {
        int u = (t >= off) ? s[t - off] : 0;
        __syncthreads();
        s[t] += u;
        __syncthreads();
    }
    if (t < nb) bsum[t] = s[t] - v;
}

// final row_ptr; fused dinv
__global__ void k_scan_add(int* __restrict__ row_ptr, const int* __restrict__ bsum,
                           const int* __restrict__ deg, float* __restrict__ dinv) {
    int i = blockIdx.x * 256 + threadIdx.x;
    if (i < NN) {
        row_ptr[i] += bsum[i >> 10];
        dinv[i] = rsqrtf((float)(deg[i] + 1));  // +1 self-loop
    }
    if (i == 0) row_ptr[NN] = EE;
}

// ---------------- scatter per sub-bin: LDS cursors, exclusive output region ----------------
__global__ __launch_bounds__(256) void k_scatter3(const unsigned* __restrict__ bins,
                                                  const unsigned* __restrict__ gtail,
                                                  const int* __restrict__ rp,
                                                  int* __restrict__ ssrc) {
    int b = blockIdx.x;
    int shard = b >> 5, sub = b & 31;
    int lo = sub * SUBW;
    int hi = lo + SUBW; if (hi > SHN) hi = SHN;
    int nn = hi - lo;
    int gbase = shard * SHN + lo;
    __shared__ int cur[SUBW];
    for (int i = threadIdx.x; i < nn; i += 256) cur[i] = rp[gbase + i];
    __syncthreads();
    unsigned m = gtail[shard];
    if (m > (unsigned)CAP) m = CAP;
    const unsigned* bb = bins + (size_t)shard * CAP;
    for (unsigned i = threadIdx.x; i < m; i += 256) {
        unsigned u = bb[i];
        int dl = (int)(u >> 17);
        if (dl >= lo && dl < hi) {
            int p = atomicAdd(&cur[dl - lo], 1);
            ssrc[p] = (int)(u & 0x1FFFFu);
        }
    }
}

// ---------------- x -> bf16 ----------------
__global__ void k_cvt(const float* __restrict__ x, unsigned short* __restrict__ xb) {
    int i = blockIdx.x * 256 + threadIdx.x;
    if (i < NN * (HH / 4)) {
        float4 v = ((const float4*)x)[i];
        ushort4 o;
        o.x = f2bf(v.x); o.y = f2bf(v.y); o.z = f2bf(v.z); o.w = f2bf(v.w);
        ((ushort4*)xb)[i] = o;
    }
}

// ---------------- GEMM: C[N,128] = A[N,128] @ W[128,128], MFMA bf16, split-W ----------------
__global__ __launch_bounds__(256) void gemm_mfma(const unsigned short* __restrict__ A,
                                                 const float* __restrict__ W,
                                                 unsigned short* __restrict__ C, int nrows) {
    __shared__ unsigned short smem[2 * 64 * 136];  // WtH | WtL ; reused as Cs[128][68]
    unsigned short* WtH = smem;
    unsigned short* WtL = smem + 64 * 136;

    int t = threadIdx.x;
    int row0 = blockIdx.x * 128;
    int c0   = blockIdx.y * 64;

    for (int idx = t; idx < 64 * 128; idx += 256) {
        int k = idx >> 6, c = idx & 63;
        float w = W[k * 128 + c0 + c];
        unsigned short hb = f2bf(w);
        unsigned short lb = f2bf(w - bf2f(hb));
        WtH[c * 136 + k] = hb;
        WtL[c * 136 + k] = lb;
    }
    __syncthreads();

    int wv = t >> 6, lane = t & 63, m = lane & 15, q = lane >> 4;
    long rowA = row0 + wv * 32 + m;
    long rowB = rowA + 16;

    f32x4 acc[2][4] = {};
    for (int kc = 0; kc < 4; ++kc) {
        int ko = kc * 32 + q * 8;
        short8 a0 = {}, a1 = {};
        if (rowA < nrows) a0 = *(const short8*)(A + rowA * 128 + ko);
        if (rowB < nrows) a1 = *(const short8*)(A + rowB * 128 + ko);
#pragma unroll
        for (int ct = 0; ct < 4; ++ct) {
            short8 bh = *(const short8*)(WtH + (ct * 16 + m) * 136 + ko);
            short8 bl = *(const short8*)(WtL + (ct * 16 + m) * 136 + ko);
            acc[0][ct] = __builtin_amdgcn_mfma_f32_16x16x32_bf16(a0, bh, acc[0][ct], 0, 0, 0);
            acc[0][ct] = __builtin_amdgcn_mfma_f32_16x16x32_bf16(a0, bl, acc[0][ct], 0, 0, 0);
            acc[1][ct] = __builtin_amdgcn_mfma_f32_16x16x32_bf16(a1, bh, acc[1][ct], 0, 0, 0);
            acc[1][ct] = __builtin_amdgcn_mfma_f32_16x16x32_bf16(a1, bl, acc[1][ct], 0, 0, 0);
        }
    }

    __syncthreads();
    unsigned short* Cs = smem;  // [128][68]
#pragma unroll
    for (int rt = 0; rt < 2; ++rt)
#pragma unroll
        for (int ct = 0; ct < 4; ++ct)
#pragma unroll
            for (int r = 0; r < 4; ++r) {
                int rl = wv * 32 + rt * 16 + q * 4 + r;
                Cs[rl * 68 + ct * 16 + m] = f2bf(acc[rt][ct][r]);
            }
    __syncthreads();
    for (int idx = t; idx < 128 * 16; idx += 256) {
        int row = idx >> 4, ch = idx & 15;
        long grow = row0 + row;
        if (grow < nrows)
            *(ushort4*)(C + grow * 128 + c0 + ch * 4) = *(const ushort4*)(Cs + row * 68 + ch * 4);
    }
}

// ---------------- aggregate + bias + BN + ReLU ----------------
// one edge per FULL wave; 64-edge metadata preload; readlane -> SGPR row base;
// 2 ch/lane packed float2 FMA; pad = self row with ds=0.
__global__ __launch_bounds__(256) void k_agg(const unsigned short* __restrict__ hw,
                                             const int* __restrict__ rp,
                                             const int* __restrict__ ssrc,
                                             const float* __restrict__ dinv,
                                             const float* __restrict__ bsl,
                                             const float* __restrict__ gamma,
                                             const float* __restrict__ beta,
                                             const float* __restrict__ rm,
                                             const float* __restrict__ rv,
                                             unsigned short* __restrict__ out) {
    int lane = threadIdx.x & 63;
    int c2   = lane * 2;                       // 2 channels per lane
    int n = blockIdx.x * 4 + (threadIdx.x >> 6);
    if (n >= NN) return;
    int beg = rp[n], end = rp[n + 1];

    v2f acc0 = {0.f, 0.f}, acc1 = {0.f, 0.f};

    for (int chunk = beg; chunk < end; chunk += 64) {
        int l = chunk + lane;
        bool valid = (l < end);
        int   e  = valid ? ssrc[l] : n;        // pad: self row (harmless, ds=0)
        float dv = valid ? dinv[e] : 0.f;
        int cnt = end - chunk;
        if (cnt > 64) cnt = 64;
        for (int jb = 0; jb < cnt; jb += 8) {
#pragma unroll
            for (int j = 0; j < 8; ++j) {
                int s    = __builtin_amdgcn_readlane(e, jb + j);
                float ds = __int_as_float(
                               __builtin_amdgcn_readlane(__float_as_int(dv), jb + j));
                unsigned u = *(const unsigned*)(hw + (size_t)s * HH + c2);
                v2f vv;
                vv.x = __int_as_float((int)(u << 16));
                vv.y = __int_as_float((int)(u & 0xffff0000u));
                v2f d2 = {ds, ds};
                if (j & 1) acc1 += d2 * vv;
                else       acc0 += d2 * vv;
            }
        }
    }
    v2f a = acc0 + acc1;

    // self-loop
    float di = dinv[n];
    {
        unsigned u = *(const unsigned*)(hw + (size_t)n * HH + c2);
        v2f vv;
        vv.x = __int_as_float((int)(u << 16));
        vv.y = __int_as_float((int)(u & 0xffff0000u));
        v2f d2 = {di, di};
        a += d2 * vv;
    }
    a.x *= di;
    a.y *= di;

    float g0 = gamma[c2],   g1 = gamma[c2 + 1];
    float r0 = rv[c2],      r1 = rv[c2 + 1];
    float s0 = g0 * rsqrtf(r0 + EPSV);
    float s1 = g1 * rsqrtf(r1 + EPSV);
    float b0 = fmaf(bsl[c2]     - rm[c2],     s0, beta[c2]);
    float b1 = fmaf(bsl[c2 + 1] - rm[c2 + 1], s1, beta[c2 + 1]);
    float y0 = fmaxf(fmaf(a.x, s0, b0), 0.f);
    float y1 = fmaxf(fmaf(a.y, s1, b1), 0.f);
    ushort2 o;
    o.x = f2bf(y0);
    o.y = f2bf(y1);
    *(ushort2*)(out + (size_t)n * HH + c2) = o;
}

// ---------------- global mean pool (batch sorted, bf16 input) ----------------
__global__ __launch_bounds__(128) void k_pool(const unsigned short* __restrict__ h,
                                              const int* __restrict__ batch,
                                              float* __restrict__ pooled,
                                              float* __restrict__ cnt) {
    int t = threadIdx.x;
    const int chunk = (NN + 1023) / 1024;
    int n0 = blockIdx.x * chunk;
    if (n0 >= NN) return;
    int n1 = n0 + chunk;
    if (n1 > NN) n1 = NN;
    int cur = batch[n0];
    float acc = 0.f;
    int k = 0;
    for (int n = n0; n < n1; ++n) {
        int b = batch[n];
        if (b != cur) {
            atomicAdd(&pooled[(size_t)cur * 128 + t], acc);
            if (t == 0) atomicAdd(&cnt[cur], (float)k);
            acc = 0.f; k = 0; cur = b;
        }
        acc += bf2f(h[(size_t)n * 128 + t]);
        ++k;
    }
    atomicAdd(&pooled[(size_t)cur * 128 + t], acc);
    if (t == 0) atomicAdd(&cnt[cur], (float)k);
}

// ---------------- LSTM (single step, h0=c0=0) + FC ----------------
__global__ __launch_bounds__(128) void k_head(const float* __restrict__ pooled,
                                              const float* __restrict__ cnt,
                                              const float* __restrict__ W_ih,
                                              const float* __restrict__ b_ih,
                                              const float* __restrict__ b_hh,
                                              const float* __restrict__ W_fc,
                                              const float* __restrict__ b_fc,
                                              float* __restrict__ out) {
    __shared__ float pm[128];
    __shared__ float gate[512];
    __shared__ float hn[128];
    int g = blockIdx.x, t = threadIdx.x;
    float cdiv = fmaxf(cnt[g], 1.0f);
    pm[t] = pooled[(size_t)g * 128 + t] / cdiv;
    __syncthreads();
    for (int j = t; j < 512; j += 128) {
        float acc = b_ih[j] + b_hh[j];
        const float* w = W_ih + (size_t)j * 128;
#pragma unroll 8
        for (int k = 0; k < 128; ++k) acc = fmaf(pm[k], w[k], acc);
        gate[j] = acc;
    }
    __syncthreads();
    {
        float gi = gate[t], gg = gate[256 + t], go = gate[384 + t];
        float cc = (1.f / (1.f + expf(-gi))) * tanhf(gg);
        hn[t] = (1.f / (1.f + expf(-go))) * tanhf(cc);
    }
    __syncthreads();
    if (t < 16) {
        float acc = b_fc[t];
        const float* w = W_fc + (size_t)t * 128;
#pragma unroll 8
        for (int k = 0; k < 128; ++k) acc = fmaf(hn[k], w[k], acc);
        out[(size_t)g * 16 + t] = acc;
    }
}

// ---------------- launch ----------------
extern "C" void kernel_launch(void* const* d_in, const int* in_sizes, int n_in,
                              void* d_out, int out_size, void* d_ws, size_t ws_size,
                              hipStream_t stream) {
    const float* x      = (const float*)d_in[0];
    const int*   ei     = (const int*)d_in[1];
    const int*   src    = ei;
    const int*   dst    = ei + EE;
    const int*   batch  = (const int*)d_in[2];
    const float* Ws     = (const float*)d_in[3];
    const float* bs     = (const float*)d_in[4];
    const float* gammas = (const float*)d_in[5];
    const float* betas  = (const float*)d_in[6];
    const float* rms    = (const float*)d_in[7];
    const float* rvs    = (const float*)d_in[8];
    const float* W_ih   = (const float*)d_in[9];
    // d_in[10] = W_hh (unused: h0 = 0)
    const float* b_ih   = (const float*)d_in[11];
    const float* b_hh   = (const float*)d_in[12];
    const float* W_fc   = (const float*)d_in[13];
    const float* b_fc   = (const float*)d_in[14];
    float* out = (float*)d_out;

    char* w = (char*)d_ws;
    unsigned*       gtail  = (unsigned*)(w + OFF_TL);
    int*            deg    = (int*)(w + OFF_DEG);
    float*          dinv   = (float*)(w + OFF_DNV);
    int*            rp     = (int*)(w + OFF_RP);
    int*            ssrc   = (int*)(w + OFF_SRC);
    unsigned*       bins   = (unsigned*)(w + OFF_BIN);
    int*            bsum   = (int*)(w + OFF_BS);
    unsigned short* xb     = (unsigned short*)(w + OFF_XB);
    unsigned short* hwb    = (unsigned short*)(w + OFF_HW);
    unsigned short* h0     = (unsigned short*)(w + OFF_H0);
    float*          pooled = (float*)(w + OFF_PL);
    float*          cntb   = pooled + (size_t)GG * HH;

    hipMemsetAsync(gtail, 0, 8 * 4, stream);
    hipMemsetAsync(pooled, 0, ((size_t)GG * HH + GG) * 4, stream);

    k_bin<<<(EE / 4 + 255) / 256, 256, 0, stream>>>(src, dst, bins, gtail);
    k_hist<<<256, 256, 0, stream>>>(bins, gtail, deg);
    const int nscan = (NN + 1023) / 1024;
    k_scan_local<<<nscan, 1024, 0, stream>>>(deg, rp, bsum);
    k_scan_blocks<<<1, 128, 0, stream>>>(bsum, nscan);
    k_scan_add<<<(NN + 255) / 256, 256, 0, stream>>>(rp, bsum, deg, dinv);
    k_scatter3<<<256, 256, 0, stream>>>(bins, gtail, rp, ssrc);
    k_cvt<<<(NN * 32 + 255) / 256, 256, 0, stream>>>(x, xb);

    const unsigned short* hin = xb;
    dim3 ggrid((NN + 127) / 128, 2);
    for (int l = 0; l < 3; ++l) {
        gemm_mfma<<<ggrid, 256, 0, stream>>>(hin, Ws + (size_t)l * 128 * 128, hwb, NN);
        k_agg<<<(NN + 3) / 4, 256, 0, stream>>>(hwb, rp, ssrc, dinv,
                                                bs + l * 128, gammas + l * 128, betas + l * 128,
                                                rms + l * 128, rvs + l * 128, h0);
        hin = h0;
    }
    k_pool<<<1024, 128, 0, stream>>>(h0, batch, pooled, cntb);
    k_head<<<GG, 128, 0, stream>>>(pooled, cntb, W_ih, b_ih, b_hh, W_fc, b_fc, out);
}

// Round 8
// 488.952 us; speedup vs baseline: 1.9177x; 1.9177x over previous
//
#include <hip/hip_runtime.h>
#include <math.h>

// ---------------- problem constants ----------------
constexpr int   NN  = 100000;    // nodes
constexpr int   EE  = 1600000;   // edges
constexpr int   HH  = 128;       // hidden / in_channels
constexpr int   GG  = 128;       // graphs
constexpr float EPSV = 1e-5f;
constexpr int   NSH = 8;         // level-1 dst shards
constexpr int   SHN = NN / NSH;  // 12500 nodes per shard
constexpr int   CAP = 210000;    // per-shard L1 bin capacity
constexpr int   NSB = 32;        // sub-bins per shard (256 total)
constexpr int   SUBW = (SHN + NSB - 1) / NSB;  // 391 nodes per sub-bin
constexpr int   CAP2 = 8192;     // per-sub-bin capacity (avg 6250, +24 sigma)
constexpr int   NCH = 64;        // bin2 chunks per shard

typedef __attribute__((ext_vector_type(8))) short  short8;
typedef __attribute__((ext_vector_type(4))) float  f32x4;
typedef __attribute__((ext_vector_type(2))) float  v2f;

__device__ __forceinline__ unsigned short f2bf(float f) {
    union { float f; unsigned u; } v; v.f = f;
    unsigned r = v.u + 0x7FFF + ((v.u >> 16) & 1);   // round-to-nearest-even
    return (unsigned short)(r >> 16);
}
__device__ __forceinline__ float bf2f(unsigned short b) {
    union { unsigned u; float f; } v; v.u = ((unsigned)b) << 16;
    return v.f;
}

// ---------------- workspace layout ----------------
constexpr size_t A256(size_t x) { return (x + 255) & ~(size_t)255; }
constexpr size_t OFF_TL  = 0;                                       // 8 + 256 uints tails (one memset)
constexpr size_t OFF_DEG = A256(OFF_TL  + (8 + 256) * 4);           // N ints (written fully by k_hist2)
constexpr size_t OFF_DNV = A256(OFF_DEG + (size_t)NN * 4);          // N floats dinv
constexpr size_t OFF_RP  = A256(OFF_DNV + (size_t)NN * 4);          // (N+1) ints
constexpr size_t OFF_SRC = A256(OFF_RP  + (size_t)(NN + 1) * 4);    // E ints sorted src
constexpr size_t OFF_BIN = A256(OFF_SRC + (size_t)EE * 4);          // 8*CAP uints L1 bins
constexpr size_t OFF_BS  = A256(OFF_BIN + (size_t)8 * CAP * 4);     // 512 ints
constexpr size_t OFF_XB  = A256(OFF_BS  + 512 * 4);                 // N*H bf16 (x); bins2 aliases here
constexpr size_t OFF_B2  = OFF_XB;                                  // 256*CAP2 uints (dead before k_cvt)
constexpr size_t OFF_HW  = A256(OFF_XB  + (size_t)NN * HH * 2);     // N*H bf16 (h@W)
constexpr size_t OFF_H0  = A256(OFF_HW  + (size_t)NN * HH * 2);     // N*H bf16 (h)
constexpr size_t OFF_PL  = A256(OFF_H0  + (size_t)NN * HH * 2);     // G*H f32 pooled + G f32 cnt

// ---------------- L1 bin: edges by dst-shard, packed (dl<<17 | src) ----------------
__global__ __launch_bounds__(256) void k_bin(const int* __restrict__ src,
                                             const int* __restrict__ dst,
                                             unsigned* __restrict__ bins,
                                             unsigned* __restrict__ gtail) {
    __shared__ unsigned sbin[8][1024];
    __shared__ unsigned scnt[8];
    __shared__ unsigned sbase[8];
    int t = threadIdx.x;
    if (t < 8) scnt[t] = 0;
    __syncthreads();
    int i = blockIdx.x * 256 + t;            // int4 index
    const int nvec = EE / 4;                 // 400000
    if (i < nvec) {
        int4 d = ((const int4*)dst)[i];
        int4 s = ((const int4*)src)[i];
        int dd[4] = {d.x, d.y, d.z, d.w};
        int ss[4] = {s.x, s.y, s.z, s.w};
#pragma unroll
        for (int c = 0; c < 4; ++c) {
            int sh = dd[c] / SHN;
            unsigned p = atomicAdd(&scnt[sh], 1u);
            sbin[sh][p] = ((unsigned)(dd[c] - sh * SHN) << 17) | (unsigned)ss[c];
        }
    }
    __syncthreads();
    if (t < 8) sbase[t] = atomicAdd(&gtail[t], scnt[t]);
    __syncthreads();
    for (int s = 0; s < 8; ++s) {
        unsigned cnt = scnt[s], base = sbase[s];
        if (base >= (unsigned)CAP) continue;
        if (base + cnt > (unsigned)CAP) cnt = CAP - base;
        for (unsigned j = t; j < cnt; j += 256)
            bins[(size_t)s * CAP + base + j] = sbin[s][j];
    }
}

// ---------------- L2 bin: shard bin -> 32 sub-bins (counting sort per chunk) ----------------
// R7 lesson: 256 blocks streaming 800 KB each = 781 latency-bound iters, 249 us.
// Fix: 64 chunk-blocks per shard counting-sort ~3.3k edges each into 32 sub-bins
// (repacked (dl2<<17|src), dl2<391); hist/scatter then stream ONLY their sub-bin.
__global__ __launch_bounds__(256) void k_bin2(const unsigned* __restrict__ bins,
                                              const unsigned* __restrict__ gtail,
                                              unsigned* __restrict__ bins2,
                                              unsigned* __restrict__ tail2) {
    __shared__ unsigned staged[(CAP + NCH - 1) / NCH + 64];  // <=3346
    __shared__ unsigned cnt[NSB], base[NSB], cur[NSB], gbase[NSB];
    int t = threadIdx.x;
    int shard = blockIdx.x >> 6, chunk = blockIdx.x & 63;
    unsigned m = gtail[shard];
    if (m > (unsigned)CAP) m = CAP;
    unsigned csz = (m + NCH - 1) / NCH;
    unsigned i0 = chunk * csz;
    unsigned i1 = i0 + csz; if (i1 > m) i1 = m;
    if (i0 >= m) return;
    const unsigned* bb = bins + (size_t)shard * CAP;

    if (t < NSB) cnt[t] = 0;
    __syncthreads();
    for (unsigned i = i0 + t; i < i1; i += 256)
        atomicAdd(&cnt[(bb[i] >> 17) / SUBW], 1u);
    __syncthreads();
    if (t == 0) {
        unsigned run = 0;
        for (int sb = 0; sb < NSB; ++sb) { base[sb] = run; run += cnt[sb]; }
    }
    __syncthreads();
    if (t < NSB) {
        gbase[t] = atomicAdd(&tail2[shard * NSB + t], cnt[t]);
        cur[t] = base[t];
    }
    __syncthreads();
    for (unsigned i = i0 + t; i < i1; i += 256) {
        unsigned u = bb[i];
        unsigned dl = u >> 17;
        unsigned sb = dl / SUBW;
        unsigned p = atomicAdd(&cur[sb], 1u);
        staged[p] = ((dl - sb * SUBW) << 17) | (u & 0x1FFFFu);
    }
    __syncthreads();
    int wv = t >> 6, ln = t & 63;
    for (int sb = wv; sb < NSB; sb += 4) {
        unsigned c = cnt[sb], gb = gbase[sb], lb = base[sb];
        if (gb >= (unsigned)CAP2) continue;
        if (gb + c > (unsigned)CAP2) c = CAP2 - gb;
        unsigned* dstp = bins2 + (size_t)(shard * NSB + sb) * CAP2 + gb;
        for (unsigned j = ln; j < c; j += 64) dstp[j] = staged[lb + j];
    }
}

// ---------------- degree histogram per sub-bin (exclusive deg writes) ----------------
__global__ __launch_bounds__(256) void k_hist2(const unsigned* __restrict__ bins2,
                                               const unsigned* __restrict__ tail2,
                                               int* __restrict__ deg) {
    int b = blockIdx.x;                      // 0..255
    int shard = b >> 5, sb = b & 31;
    int lo = sb * SUBW;
    int hi = lo + SUBW; if (hi > SHN) hi = SHN;
    int nn = hi - lo;
    __shared__ int hist[SUBW];
    int t = threadIdx.x;
    for (int i = t; i < nn; i += 256) hist[i] = 0;
    __syncthreads();
    unsigned m = tail2[b];
    if (m > (unsigned)CAP2) m = CAP2;
    const unsigned* bb = bins2 + (size_t)b * CAP2;
    unsigned nv = m >> 2;
    for (unsigned i = t; i < nv; i += 256) {
        uint4 u = ((const uint4*)bb)[i];
        atomicAdd(&hist[u.x >> 17], 1);
        atomicAdd(&hist[u.y >> 17], 1);
        atomicAdd(&hist[u.z >> 17], 1);
        atomicAdd(&hist[u.w >> 17], 1);
    }
    for (unsigned i = (m & ~3u) + t; i < m; i += 256)
        atomicAdd(&hist[bb[i] >> 17], 1);
    __syncthreads();
    int gbase = shard * SHN + lo;
    for (int i = t; i < nn; i += 256) deg[gbase + i] = hist[i];
}

__global__ __launch_bounds__(1024) void k_scan_local(const int* __restrict__ deg,
                                                     int* __restrict__ row_ptr,
                                                     int* __restrict__ bsum) {
    __shared__ int s[1024];
    int t = threadIdx.x;
    int i = blockIdx.x * 1024 + t;
    int v = (i < NN) ? deg[i] : 0;
    s[t] = v;
    __syncthreads();
    for (int off = 1; off < 1024; off <<= 1) {
        int u = (t >= off) ? s[t - off] : 0;
        __syncthreads();
        s[t] += u;
        __syncthreads();
    }
    if (i < NN) row_ptr[i] = s[t] - v;
    if (t == 1023) bsum[blockIdx.x] = s[1023];
}

__global__ void k_scan_blocks(int* __restrict__ bsum, int nb) {
    __shared__ int s[128];
    int t = threadIdx.x;
    int v = (t < nb) ? bsum[t] : 0;
    s[t] = v;
    __syncthreads();
    for (int off = 1; off < 128; off <<= 1) {
        int u = (t >= off) ? s[t - off] : 0;
        __syncthreads();
        s[t] += u;
        __syncthreads();
    }
    if (t < nb) bsum[t] = s[t] - v;
}

// final row_ptr; fused dinv
__global__ void k_scan_add(int* __restrict__ row_ptr, const int* __restrict__ bsum,
                           const int* __restrict__ deg, float* __restrict__ dinv) {
    int i = blockIdx.x * 256 + threadIdx.x;
    if (i < NN) {
        row_ptr[i] += bsum[i >> 10];
        dinv[i] = rsqrtf((float)(deg[i] + 1));  // +1 self-loop
    }
    if (i == 0) row_ptr[NN] = EE;
}

// ---------------- scatter per sub-bin: LDS cursors, exclusive ssrc region ----------------
__global__ __launch_bounds__(256) void k_scatter4(const unsigned* __restrict__ bins2,
                                                  const unsigned* __restrict__ tail2,
                                                  const int* __restrict__ rp,
                                                  int* __restrict__ ssrc) {
    int b = blockIdx.x;
    int shard = b >> 5, sb = b & 31;
    int lo = sb * SUBW;
    int hi = lo + SUBW; if (hi > SHN) hi = SHN;
    int nn = hi - lo;
    int gbase = shard * SHN + lo;
    __shared__ int cur[SUBW];
    int t = threadIdx.x;
    for (int i = t; i < nn; i += 256) cur[i] = rp[gbase + i];
    __syncthreads();
    unsigned m = tail2[b];
    if (m > (unsigned)CAP2) m = CAP2;
    const unsigned* bb = bins2 + (size_t)b * CAP2;
    unsigned nv = m >> 2;
    for (unsigned i = t; i < nv; i += 256) {
        uint4 u = ((const uint4*)bb)[i];
        int p;
        p = atomicAdd(&cur[u.x >> 17], 1); ssrc[p] = (int)(u.x & 0x1FFFFu);
        p = atomicAdd(&cur[u.y >> 17], 1); ssrc[p] = (int)(u.y & 0x1FFFFu);
        p = atomicAdd(&cur[u.z >> 17], 1); ssrc[p] = (int)(u.z & 0x1FFFFu);
        p = atomicAdd(&cur[u.w >> 17], 1); ssrc[p] = (int)(u.w & 0x1FFFFu);
    }
    for (unsigned i = (m & ~3u) + t; i < m; i += 256) {
        unsigned u = bb[i];
        int p = atomicAdd(&cur[u >> 17], 1);
        ssrc[p] = (int)(u & 0x1FFFFu);
    }
}

// ---------------- x -> bf16 ----------------
__global__ void k_cvt(const float* __restrict__ x, unsigned short* __restrict__ xb) {
    int i = blockIdx.x * 256 + threadIdx.x;
    if (i < NN * (HH / 4)) {
        float4 v = ((const float4*)x)[i];
        ushort4 o;
        o.x = f2bf(v.x); o.y = f2bf(v.y); o.z = f2bf(v.z); o.w = f2bf(v.w);
        ((ushort4*)xb)[i] = o;
    }
}

// ---------------- GEMM: C[N,128] = A[N,128] @ W[128,128], MFMA bf16, split-W ----------------
__global__ __launch_bounds__(256) void gemm_mfma(const unsigned short* __restrict__ A,
                                                 const float* __restrict__ W,
                                                 unsigned short* __restrict__ C, int nrows) {
    __shared__ unsigned short smem[2 * 64 * 136];  // WtH | WtL ; reused as Cs[128][68]
    unsigned short* WtH = smem;
    unsigned short* WtL = smem + 64 * 136;

    int t = threadIdx.x;
    int row0 = blockIdx.x * 128;
    int c0   = blockIdx.y * 64;

    for (int idx = t; idx < 64 * 128; idx += 256) {
        int k = idx >> 6, c = idx & 63;
        float w = W[k * 128 + c0 + c];
        unsigned short hb = f2bf(w);
        unsigned short lb = f2bf(w - bf2f(hb));
        WtH[c * 136 + k] = hb;
        WtL[c * 136 + k] = lb;
    }
    __syncthreads();

    int wv = t >> 6, lane = t & 63, m = lane & 15, q = lane >> 4;
    long rowA = row0 + wv * 32 + m;
    long rowB = rowA + 16;

    f32x4 acc[2][4] = {};
    for (int kc = 0; kc < 4; ++kc) {
        int ko = kc * 32 + q * 8;
        short8 a0 = {}, a1 = {};
        if (rowA < nrows) a0 = *(const short8*)(A + rowA * 128 + ko);
        if (rowB < nrows) a1 = *(const short8*)(A + rowB * 128 + ko);
#pragma unroll
        for (int ct = 0; ct < 4; ++ct) {
            short8 bh = *(const short8*)(WtH + (ct * 16 + m) * 136 + ko);
            short8 bl = *(const short8*)(WtL + (ct * 16 + m) * 136 + ko);
            acc[0][ct] = __builtin_amdgcn_mfma_f32_16x16x32_bf16(a0, bh, acc[0][ct], 0, 0, 0);
            acc[0][ct] = __builtin_amdgcn_mfma_f32_16x16x32_bf16(a0, bl, acc[0][ct], 0, 0, 0);
            acc[1][ct] = __builtin_amdgcn_mfma_f32_16x16x32_bf16(a1, bh, acc[1][ct], 0, 0, 0);
            acc[1][ct] = __builtin_amdgcn_mfma_f32_16x16x32_bf16(a1, bl, acc[1][ct], 0, 0, 0);
        }
    }

    __syncthreads();
    unsigned short* Cs = smem;  // [128][68]
#pragma unroll
    for (int rt = 0; rt < 2; ++rt)
#pragma unroll
        for (int ct = 0; ct < 4; ++ct)
#pragma unroll
            for (int r = 0; r < 4; ++r) {
                int rl = wv * 32 + rt * 16 + q * 4 + r;
                Cs[rl * 68 + ct * 16 + m] = f2bf(acc[rt][ct][r]);
            }
    __syncthreads();
    for (int idx = t; idx < 128 * 16; idx += 256) {
        int row = idx >> 4, ch = idx & 15;
        long grow = row0 + row;
        if (grow < nrows)
            *(ushort4*)(C + grow * 128 + c0 + ch * 4) = *(const ushort4*)(Cs + row * 68 + ch * 4);
    }
}

// ---------------- aggregate + bias + BN + ReLU ----------------
// one edge per FULL wave; 64-edge metadata preload; readlane -> SGPR row base;
// 2 ch/lane packed float2 FMA; pad = self row with ds=0.
__global__ __launch_bounds__(256) void k_agg(const unsigned short* __restrict__ hw,
                                             const int* __restrict__ rp,
                                             const int* __restrict__ ssrc,
                                             const float* __restrict__ dinv,
                                             const float* __restrict__ bsl,
                                             const float* __restrict__ gamma,
                                             const float* __restrict__ beta,
                                             const float* __restrict__ rm,
                                             const float* __restrict__ rv,
                                             unsigned short* __restrict__ out) {
    int lane = threadIdx.x & 63;
    int c2   = lane * 2;                       // 2 channels per lane
    int n = blockIdx.x * 4 + (threadIdx.x >> 6);
    if (n >= NN) return;
    int beg = rp[n], end = rp[n + 1];

    v2f acc0 = {0.f, 0.f}, acc1 = {0.f, 0.f};

    for (int chunk = beg; chunk < end; chunk += 64) {
        int l = chunk + lane;
        bool valid = (l < end);
        int   e  = valid ? ssrc[l] : n;        // pad: self row (harmless, ds=0)
        float dv = valid ? dinv[e] : 0.f;
        int cnt = end - chunk;
        if (cnt > 64) cnt = 64;
        for (int jb = 0; jb < cnt; jb += 8) {
#pragma unroll
            for (int j = 0; j < 8; ++j) {
                int s    = __builtin_amdgcn_readlane(e, jb + j);
                float ds = __int_as_float(
                               __builtin_amdgcn_readlane(__float_as_int(dv), jb + j));
                unsigned u = *(const unsigned*)(hw + (size_t)s * HH + c2);
                v2f vv;
                vv.x = __int_as_float((int)(u << 16));
                vv.y = __int_as_float((int)(u & 0xffff0000u));
                v2f d2 = {ds, ds};
                if (j & 1) acc1 += d2 * vv;
                else       acc0 += d2 * vv;
            }
        }
    }
    v2f a = acc0 + acc1;

    // self-loop
    float di = dinv[n];
    {
        unsigned u = *(const unsigned*)(hw + (size_t)n * HH + c2);
        v2f vv;
        vv.x = __int_as_float((int)(u << 16));
        vv.y = __int_as_float((int)(u & 0xffff0000u));
        v2f d2 = {di, di};
        a += d2 * vv;
    }
    a.x *= di;
    a.y *= di;

    float g0 = gamma[c2],   g1 = gamma[c2 + 1];
    float r0 = rv[c2],      r1 = rv[c2 + 1];
    float s0 = g0 * rsqrtf(r0 + EPSV);
    float s1 = g1 * rsqrtf(r1 + EPSV);
    float b0 = fmaf(bsl[c2]     - rm[c2],     s0, beta[c2]);
    float b1 = fmaf(bsl[c2 + 1] - rm[c2 + 1], s1, beta[c2 + 1]);
    float y0 = fmaxf(fmaf(a.x, s0, b0), 0.f);
    float y1 = fmaxf(fmaf(a.y, s1, b1), 0.f);
    ushort2 o;
    o.x = f2bf(y0);
    o.y = f2bf(y1);
    *(ushort2*)(out + (size_t)n * HH + c2) = o;
}

// ---------------- global mean pool (batch sorted, bf16 input) ----------------
__global__ __launch_bounds__(128) void k_pool(const unsigned short* __restrict__ h,
                                              const int* __restrict__ batch,
                                              float* __restrict__ pooled,
                                              float* __restrict__ cnt) {
    int t = threadIdx.x;
    const int chunk = (NN + 1023) / 1024;
    int n0 = blockIdx.x * chunk;
    if (n0 >= NN) return;
    int n1 = n0 + chunk;
    if (n1 > NN) n1 = NN;
    int cur = batch[n0];
    float acc = 0.f;
    int k = 0;
    for (int n = n0; n < n1; ++n) {
        int b = batch[n];
        if (b != cur) {
            atomicAdd(&pooled[(size_t)cur * 128 + t], acc);
            if (t == 0) atomicAdd(&cnt[cur], (float)k);
            acc = 0.f; k = 0; cur = b;
        }
        acc += bf2f(h[(size_t)n * 128 + t]);
        ++k;
    }
    atomicAdd(&pooled[(size_t)cur * 128 + t], acc);
    if (t == 0) atomicAdd(&cnt[cur], (float)k);
}

// ---------------- LSTM (single step, h0=c0=0) + FC ----------------
__global__ __launch_bounds__(128) void k_head(const float* __restrict__ pooled,
                                              const float* __restrict__ cnt,
                                              const float* __restrict__ W_ih,
                                              const float* __restrict__ b_ih,
                                              const float* __restrict__ b_hh,
                                              const float* __restrict__ W_fc,
                                              const float* __restrict__ b_fc,
                                              float* __restrict__ out) {
    __shared__ float pm[128];
    __shared__ float gate[512];
    __shared__ float hn[128];
    int g = blockIdx.x, t = threadIdx.x;
    float cdiv = fmaxf(cnt[g], 1.0f);
    pm[t] = pooled[(size_t)g * 128 + t] / cdiv;
    __syncthreads();
    for (int j = t; j < 512; j += 128) {
        float acc = b_ih[j] + b_hh[j];
        const float* w = W_ih + (size_t)j * 128;
#pragma unroll 8
        for (int k = 0; k < 128; ++k) acc = fmaf(pm[k], w[k], acc);
        gate[j] = acc;
    }
    __syncthreads();
    {
        float gi = gate[t], gg = gate[256 + t], go = gate[384 + t];
        float cc = (1.f / (1.f + expf(-gi))) * tanhf(gg);
        hn[t] = (1.f / (1.f + expf(-go))) * tanhf(cc);
    }
    __syncthreads();
    if (t < 16) {
        float acc = b_fc[t];
        const float* w = W_fc + (size_t)t * 128;
#pragma unroll 8
        for (int k = 0; k < 128; ++k) acc = fmaf(hn[k], w[k], acc);
        out[(size_t)g * 16 + t] = acc;
    }
}

// ---------------- launch ----------------
extern "C" void kernel_launch(void* const* d_in, const int* in_sizes, int n_in,
                              void* d_out, int out_size, void* d_ws, size_t ws_size,
                              hipStream_t stream) {
    const float* x      = (const float*)d_in[0];
    const int*   ei     = (const int*)d_in[1];
    const int*   src    = ei;
    const int*   dst    = ei + EE;
    const int*   batch  = (const int*)d_in[2];
    const float* Ws     = (const float*)d_in[3];
    const float* bs     = (const float*)d_in[4];
    const float* gammas = (const float*)d_in[5];
    const float* betas  = (const float*)d_in[6];
    const float* rms    = (const float*)d_in[7];
    const float* rvs    = (const float*)d_in[8];
    const float* W_ih   = (const float*)d_in[9];
    // d_in[10] = W_hh (unused: h0 = 0)
    const float* b_ih   = (const float*)d_in[11];
    const float* b_hh   = (const float*)d_in[12];
    const float* W_fc   = (const float*)d_in[13];
    const float* b_fc   = (const float*)d_in[14];
    float* out = (float*)d_out;

    char* w = (char*)d_ws;
    unsigned*       gtail  = (unsigned*)(w + OFF_TL);      // 8 L1 tails
    unsigned*       tail2  = gtail + 8;                    // 256 L2 tails
    int*            deg    = (int*)(w + OFF_DEG);
    float*          dinv   = (float*)(w + OFF_DNV);
    int*            rp     = (int*)(w + OFF_RP);
    int*            ssrc   = (int*)(w + OFF_SRC);
    unsigned*       bins   = (unsigned*)(w + OFF_BIN);
    unsigned*       bins2  = (unsigned*)(w + OFF_B2);      // aliases xb (disjoint liveness)
    int*            bsum   = (int*)(w + OFF_BS);
    unsigned short* xb     = (unsigned short*)(w + OFF_XB);
    unsigned short* hwb    = (unsigned short*)(w + OFF_HW);
    unsigned short* h0     = (unsigned short*)(w + OFF_H0);
    float*          pooled = (float*)(w + OFF_PL);
    float*          cntb   = pooled + (size_t)GG * HH;

    hipMemsetAsync(gtail, 0, (8 + 256) * 4, stream);
    hipMemsetAsync(pooled, 0, ((size_t)GG * HH + GG) * 4, stream);

    k_bin<<<(EE / 4 + 255) / 256, 256, 0, stream>>>(src, dst, bins, gtail);
    k_bin2<<<NSH * NCH, 256, 0, stream>>>(bins, gtail, bins2, tail2);
    k_hist2<<<256, 256, 0, stream>>>(bins2, tail2, deg);
    const int nscan = (NN + 1023) / 1024;
    k_scan_local<<<nscan, 1024, 0, stream>>>(deg, rp, bsum);
    k_scan_blocks<<<1, 128, 0, stream>>>(bsum, nscan);
    k_scan_add<<<(NN + 255) / 256, 256, 0, stream>>>(rp, bsum, deg, dinv);
    k_scatter4<<<256, 256, 0, stream>>>(bins2, tail2, rp, ssrc);
    k_cvt<<<(NN * 32 + 255) / 256, 256, 0, stream>>>(x, xb);

    const unsigned short* hin = xb;
    dim3 ggrid((NN + 127) / 128, 2);
    for (int l = 0; l < 3; ++l) {
        gemm_mfma<<<ggrid, 256, 0, stream>>>(hin, Ws + (size_t)l * 128 * 128, hwb, NN);
        k_agg<<<(NN + 3) / 4, 256, 0, stream>>>(hwb, rp, ssrc, dinv,
                                                bs + l * 128, gammas + l * 128, betas + l * 128,
                                                rms + l * 128, rvs + l * 128, h0);
        hin = h0;
    }
    k_pool<<<1024, 128, 0, stream>>>(h0, batch, pooled, cntb);
    k_head<<<GG, 128, 0, stream>>>(pooled, cntb, W_ih, b_ih, b_hh, W_fc, b_fc, out);
}

// Round 9
// 475.504 us; speedup vs baseline: 1.9720x; 1.0283x over previous
//
#include <hip/hip_runtime.h>
#include <math.h>

// ---------------- problem constants ----------------
constexpr int   NN  = 100000;    // nodes
constexpr int   EE  = 1600000;   // edges
constexpr int   HH  = 128;       // hidden / in_channels
constexpr int   GG  = 128;       // graphs
constexpr float EPSV = 1e-5f;
constexpr int   NSH = 8;         // level-1 dst shards
constexpr int   SHN = NN / NSH;  // 12500 nodes per shard
constexpr int   CAP = 210000;    // per-shard L1 bin capacity
constexpr int   NSB = 32;        // sub-bins per shard (256 total)
constexpr int   SUBW = (SHN + NSB - 1) / NSB;  // 391 nodes per sub-bin
constexpr int   CAP2 = 8192;     // per-sub-bin capacity (avg 6250, +24 sigma)
constexpr int   NCH = 64;        // bin2 chunks per shard

typedef __attribute__((ext_vector_type(8))) short  short8;
typedef __attribute__((ext_vector_type(4))) float  f32x4;
typedef __attribute__((ext_vector_type(2))) float  v2f;

__device__ __forceinline__ unsigned short f2bf(float f) {
    union { float f; unsigned u; } v; v.f = f;
    unsigned r = v.u + 0x7FFF + ((v.u >> 16) & 1);   // round-to-nearest-even
    return (unsigned short)(r >> 16);
}
__device__ __forceinline__ float bf2f(unsigned short b) {
    union { unsigned u; float f; } v; v.u = ((unsigned)b) << 16;
    return v.f;
}

// ---------------- workspace layout ----------------
constexpr size_t A256(size_t x) { return (x + 255) & ~(size_t)255; }
constexpr size_t OFF_TL  = 0;                                       // gtail[8] | tail2[256] | sbase[256]
constexpr size_t OFF_DNV = A256(OFF_TL  + (8 + 256 + 256) * 4);     // N floats dinv
constexpr size_t OFF_RP  = A256(OFF_DNV + (size_t)NN * 4);          // (N+1) ints
constexpr size_t OFF_SRC = A256(OFF_RP  + (size_t)(NN + 1) * 4);    // E ints sorted src
constexpr size_t OFF_BIN = A256(OFF_SRC + (size_t)EE * 4);          // 8*CAP uints L1 bins
constexpr size_t OFF_B2  = A256(OFF_BIN + (size_t)8 * CAP * 4);     // 256*CAP2 uints L2 bins
constexpr size_t OFF_HW  = A256(OFF_B2  + (size_t)256 * CAP2 * 4);  // N*H bf16 (h@W)
constexpr size_t OFF_H0  = A256(OFF_HW  + (size_t)NN * HH * 2);     // N*H bf16 (h)
constexpr size_t OFF_PL  = A256(OFF_H0  + (size_t)NN * HH * 2);     // G*H f32 pooled + G f32 cnt

// ---------------- L1 bin: edges by dst-shard, packed (dl<<17 | src) ----------------
__global__ __launch_bounds__(256) void k_bin(const int* __restrict__ src,
                                             const int* __restrict__ dst,
                                             unsigned* __restrict__ bins,
                                             unsigned* __restrict__ gtail) {
    __shared__ unsigned sbin[8][1024];
    __shared__ unsigned scnt[8];
    __shared__ unsigned sbase[8];
    int t = threadIdx.x;
    if (t < 8) scnt[t] = 0;
    __syncthreads();
    int i = blockIdx.x * 256 + t;            // int4 index
    const int nvec = EE / 4;                 // 400000
    if (i < nvec) {
        int4 d = ((const int4*)dst)[i];
        int4 s = ((const int4*)src)[i];
        int dd[4] = {d.x, d.y, d.z, d.w};
        int ss[4] = {s.x, s.y, s.z, s.w};
#pragma unroll
        for (int c = 0; c < 4; ++c) {
            int sh = dd[c] / SHN;
            unsigned p = atomicAdd(&scnt[sh], 1u);
            sbin[sh][p] = ((unsigned)(dd[c] - sh * SHN) << 17) | (unsigned)ss[c];
        }
    }
    __syncthreads();
    if (t < 8) sbase[t] = atomicAdd(&gtail[t], scnt[t]);
    __syncthreads();
    for (int s = 0; s < 8; ++s) {
        unsigned cnt = scnt[s], base = sbase[s];
        if (base >= (unsigned)CAP) continue;
        if (base + cnt > (unsigned)CAP) cnt = CAP - base;
        for (unsigned j = t; j < cnt; j += 256)
            bins[(size_t)s * CAP + base + j] = sbin[s][j];
    }
}

// ---------------- L2 bin: shard bin -> 32 sub-bins (counting sort per chunk) ----------------
__global__ __launch_bounds__(256) void k_bin2(const unsigned* __restrict__ bins,
                                              const unsigned* __restrict__ gtail,
                                              unsigned* __restrict__ bins2,
                                              unsigned* __restrict__ tail2) {
    __shared__ unsigned staged[(CAP + NCH - 1) / NCH + 64];
    __shared__ unsigned cnt[NSB], base[NSB], cur[NSB], gbase[NSB];
    int t = threadIdx.x;
    int shard = blockIdx.x >> 6, chunk = blockIdx.x & 63;
    unsigned m = gtail[shard];
    if (m > (unsigned)CAP) m = CAP;
    unsigned csz = (m + NCH - 1) / NCH;
    unsigned i0 = chunk * csz;
    unsigned i1 = i0 + csz; if (i1 > m) i1 = m;
    if (i0 >= m) return;
    const unsigned* bb = bins + (size_t)shard * CAP;

    if (t < NSB) cnt[t] = 0;
    __syncthreads();
    for (unsigned i = i0 + t; i < i1; i += 256)
        atomicAdd(&cnt[(bb[i] >> 17) / SUBW], 1u);
    __syncthreads();
    if (t == 0) {
        unsigned run = 0;
        for (int sb = 0; sb < NSB; ++sb) { base[sb] = run; run += cnt[sb]; }
    }
    __syncthreads();
    if (t < NSB) {
        gbase[t] = atomicAdd(&tail2[shard * NSB + t], cnt[t]);
        cur[t] = base[t];
    }
    __syncthreads();
    for (unsigned i = i0 + t; i < i1; i += 256) {
        unsigned u = bb[i];
        unsigned dl = u >> 17;
        unsigned sb = dl / SUBW;
        unsigned p = atomicAdd(&cur[sb], 1u);
        staged[p] = ((dl - sb * SUBW) << 17) | (u & 0x1FFFFu);
    }
    __syncthreads();
    int wv = t >> 6, ln = t & 63;
    for (int sb = wv; sb < NSB; sb += 4) {
        unsigned c = cnt[sb], gb = gbase[sb], lb = base[sb];
        if (gb >= (unsigned)CAP2) continue;
        if (gb + c > (unsigned)CAP2) c = CAP2 - gb;
        unsigned* dstp = bins2 + (size_t)(shard * NSB + sb) * CAP2 + gb;
        for (unsigned j = ln; j < c; j += 64) dstp[j] = staged[lb + j];
    }
}

// ---------------- tail2 prefix scan (1 block) + zero pooled ----------------
// sub-bin edge totals ARE the per-sub-bin row_ptr bases -> no global deg scan
// chain needed (replaces 3 scan kernels + deg array from R8).
__global__ __launch_bounds__(256) void k_tailscan(const unsigned* __restrict__ tail2,
                                                  unsigned* __restrict__ sbase,
                                                  float* __restrict__ pooled) {
    __shared__ unsigned sa[256], sd[256];
    int t = threadIdx.x;
    unsigned v = tail2[t];
    sa[t] = v;
    __syncthreads();
    unsigned* s = sa; unsigned* d = sd;
    for (int off = 1; off < 256; off <<= 1) {
        d[t] = s[t] + ((t >= off) ? s[t - off] : 0u);
        __syncthreads();
        unsigned* tmp = s; s = d; d = tmp;
    }
    sbase[t] = s[t] - v;   // exclusive prefix in global node order
    for (int i = t; i < GG * HH + GG; i += 256) pooled[i] = 0.f;
}

// ---------------- fused hist + local scan -> rp + dinv per sub-bin ----------------
__global__ __launch_bounds__(256) void k_hist3(const unsigned* __restrict__ bins2,
                                               const unsigned* __restrict__ tail2,
                                               const unsigned* __restrict__ sbase,
                                               int* __restrict__ rp,
                                               float* __restrict__ dinv) {
    int b = blockIdx.x;                      // 0..255
    int shard = b >> 5, sb = b & 31;
    int lo = sb * SUBW;
    int hi = lo + SUBW; if (hi > SHN) hi = SHN;
    int nn = hi - lo;
    int gbase = shard * SHN + lo;
    __shared__ int hist[SUBW];
    __shared__ int sa[512], sd[512];
    int t = threadIdx.x;
    for (int i = t; i < nn; i += 256) hist[i] = 0;
    __syncthreads();
    unsigned m = tail2[b];
    if (m > (unsigned)CAP2) m = CAP2;
    const unsigned* bb = bins2 + (size_t)b * CAP2;
    unsigned nv = m >> 2;
    for (unsigned i = t; i < nv; i += 256) {
        uint4 u = ((const uint4*)bb)[i];
        atomicAdd(&hist[u.x >> 17], 1);
        atomicAdd(&hist[u.y >> 17], 1);
        atomicAdd(&hist[u.z >> 17], 1);
        atomicAdd(&hist[u.w >> 17], 1);
    }
    for (unsigned i = (m & ~3u) + t; i < m; i += 256)
        atomicAdd(&hist[bb[i] >> 17], 1);
    __syncthreads();
    // inclusive Hillis-Steele over 512 (padded), 2 elems/thread, ping-pong
    sa[t]       = (t < nn)       ? hist[t]       : 0;
    sa[t + 256] = (t + 256 < nn) ? hist[t + 256] : 0;
    __syncthreads();
    int* s = sa; int* d = sd;
    for (int off = 1; off < 512; off <<= 1) {
        d[t]       = s[t]       + ((t >= off)       ? s[t - off]       : 0);
        d[t + 256] = s[t + 256] + ((t + 256 >= off) ? s[t + 256 - off] : 0);
        __syncthreads();
        int* tmp = s; s = d; d = tmp;
    }
    unsigned base = sbase[b];
    for (int i = t; i < nn; i += 256) {
        rp[gbase + i]   = (int)(base + (i ? (unsigned)s[i - 1] : 0u));
        dinv[gbase + i] = rsqrtf((float)(hist[i] + 1));  // +1 self-loop
    }
    if (b == 255 && t == 0) rp[NN] = EE;
}

// ---------------- scatter per sub-bin: LDS cursors, exclusive ssrc region ----------------
__global__ __launch_bounds__(256) void k_scatter4(const unsigned* __restrict__ bins2,
                                                  const unsigned* __restrict__ tail2,
                                                  const int* __restrict__ rp,
                                                  int* __restrict__ ssrc) {
    int b = blockIdx.x;
    int shard = b >> 5, sb = b & 31;
    int lo = sb * SUBW;
    int hi = lo + SUBW; if (hi > SHN) hi = SHN;
    int nn = hi - lo;
    int gbase = shard * SHN + lo;
    __shared__ int cur[SUBW];
    int t = threadIdx.x;
    for (int i = t; i < nn; i += 256) cur[i] = rp[gbase + i];
    __syncthreads();
    unsigned m = tail2[b];
    if (m > (unsigned)CAP2) m = CAP2;
    const unsigned* bb = bins2 + (size_t)b * CAP2;
    unsigned nv = m >> 2;
    for (unsigned i = t; i < nv; i += 256) {
        uint4 u = ((const uint4*)bb)[i];
        int p;
        p = atomicAdd(&cur[u.x >> 17], 1); ssrc[p] = (int)(u.x & 0x1FFFFu);
        p = atomicAdd(&cur[u.y >> 17], 1); ssrc[p] = (int)(u.y & 0x1FFFFu);
        p = atomicAdd(&cur[u.z >> 17], 1); ssrc[p] = (int)(u.z & 0x1FFFFu);
        p = atomicAdd(&cur[u.w >> 17], 1); ssrc[p] = (int)(u.w & 0x1FFFFu);
    }
    for (unsigned i = (m & ~3u) + t; i < m; i += 256) {
        unsigned u = bb[i];
        int p = atomicAdd(&cur[u >> 17], 1);
        ssrc[p] = (int)(u & 0x1FFFFu);
    }
}

// ---------------- GEMM: C[N,128] = A[N,128] @ W[128,128], MFMA bf16, split-W ----------------
// R9: A fragments preloaded ONCE into regs; both 64-col halves computed by the
// same block (two W-stage phases) -> A read once, not twice. FP32A template
// reads fp32 x directly for layer 0 (k_cvt kernel deleted).
template<bool FP32A>
__global__ __launch_bounds__(256) void gemm_mfma(const void* __restrict__ Ap,
                                                 const float* __restrict__ W,
                                                 unsigned short* __restrict__ C, int nrows) {
    __shared__ unsigned short WtH[64 * 136];  // reused as Cs[128][68] in epilogue
    __shared__ unsigned short WtL[64 * 136];
    int t = threadIdx.x;
    int row0 = blockIdx.x * 128;
    int wv = t >> 6, lane = t & 63, m = lane & 15, q = lane >> 4;
    long rowA = row0 + wv * 32 + m;
    long rowB = rowA + 16;

    // preload A fragments for full K once
    short8 a[2][4];
#pragma unroll
    for (int kc = 0; kc < 4; ++kc) {
        int ko = kc * 32 + q * 8;
        if (FP32A) {
            const float* Af = (const float*)Ap;
            float4 f0 = {0,0,0,0}, f1 = {0,0,0,0}, g0 = {0,0,0,0}, g1 = {0,0,0,0};
            if (rowA < nrows) {
                f0 = *(const float4*)(Af + rowA * 128 + ko);
                f1 = *(const float4*)(Af + rowA * 128 + ko + 4);
            }
            if (rowB < nrows) {
                g0 = *(const float4*)(Af + rowB * 128 + ko);
                g1 = *(const float4*)(Af + rowB * 128 + ko + 4);
            }
            union { short8 s; unsigned short u[8]; } ua, ub;
            ua.u[0] = f2bf(f0.x); ua.u[1] = f2bf(f0.y); ua.u[2] = f2bf(f0.z); ua.u[3] = f2bf(f0.w);
            ua.u[4] = f2bf(f1.x); ua.u[5] = f2bf(f1.y); ua.u[6] = f2bf(f1.z); ua.u[7] = f2bf(f1.w);
            ub.u[0] = f2bf(g0.x); ub.u[1] = f2bf(g0.y); ub.u[2] = f2bf(g0.z); ub.u[3] = f2bf(g0.w);
            ub.u[4] = f2bf(g1.x); ub.u[5] = f2bf(g1.y); ub.u[6] = f2bf(g1.z); ub.u[7] = f2bf(g1.w);
            a[0][kc] = ua.s; a[1][kc] = ub.s;
        } else {
            const unsigned short* Ab = (const unsigned short*)Ap;
            short8 z = {};
            a[0][kc] = (rowA < nrows) ? *(const short8*)(Ab + rowA * 128 + ko) : z;
            a[1][kc] = (rowB < nrows) ? *(const short8*)(Ab + rowB * 128 + ko) : z;
        }
    }

    for (int half = 0; half < 2; ++half) {
        int c0 = half * 64;
        __syncthreads();  // prior epilogue's Cs reads complete before restage
        for (int idx = t; idx < 64 * 128; idx += 256) {
            int k = idx >> 6, c = idx & 63;
            float w = W[k * 128 + c0 + c];
            unsigned short hb = f2bf(w);
            WtH[c * 136 + k] = hb;
            WtL[c * 136 + k] = f2bf(w - bf2f(hb));
        }
        __syncthreads();
        f32x4 acc[2][4] = {};
#pragma unroll
        for (int kc = 0; kc < 4; ++kc) {
            int ko = kc * 32 + q * 8;
#pragma unroll
            for (int ct = 0; ct < 4; ++ct) {
                short8 bh = *(const short8*)(WtH + (ct * 16 + m) * 136 + ko);
                short8 bl = *(const short8*)(WtL + (ct * 16 + m) * 136 + ko);
                acc[0][ct] = __builtin_amdgcn_mfma_f32_16x16x32_bf16(a[0][kc], bh, acc[0][ct], 0, 0, 0);
                acc[0][ct] = __builtin_amdgcn_mfma_f32_16x16x32_bf16(a[0][kc], bl, acc[0][ct], 0, 0, 0);
                acc[1][ct] = __builtin_amdgcn_mfma_f32_16x16x32_bf16(a[1][kc], bh, acc[1][ct], 0, 0, 0);
                acc[1][ct] = __builtin_amdgcn_mfma_f32_16x16x32_bf16(a[1][kc], bl, acc[1][ct], 0, 0, 0);
            }
        }
        __syncthreads();
        unsigned short* Cs = WtH;  // [128][68]
#pragma unroll
        for (int rt = 0; rt < 2; ++rt)
#pragma unroll
            for (int ct = 0; ct < 4; ++ct)
#pragma unroll
                for (int r = 0; r < 4; ++r) {
                    int rl = wv * 32 + rt * 16 + q * 4 + r;
                    Cs[rl * 68 + ct * 16 + m] = f2bf(acc[rt][ct][r]);
                }
        __syncthreads();
        for (int idx = t; idx < 128 * 16; idx += 256) {
            int row = idx >> 4, ch = idx & 15;
            long grow = row0 + row;
            if (grow < nrows)
                *(ushort4*)(C + grow * 128 + c0 + ch * 4) = *(const ushort4*)(Cs + row * 68 + ch * 4);
        }
    }
}

// ---------------- aggregate + bias + BN + ReLU ----------------
// one edge per FULL wave; 64-edge metadata preload; readlane -> SGPR row base;
// 2 ch/lane packed float2 FMA; pad = self row with ds=0.
__global__ __launch_bounds__(256) void k_agg(const unsigned short* __restrict__ hw,
                                             const int* __restrict__ rp,
                                             const int* __restrict__ ssrc,
                                             const float* __restrict__ dinv,
                                             const float* __restrict__ bsl,
                                             const float* __restrict__ gamma,
                                             const float* __restrict__ beta,
                                             const float* __restrict__ rm,
                                             const float* __restrict__ rv,
                                             unsigned short* __restrict__ out) {
    int lane = threadIdx.x & 63;
    int c2   = lane * 2;                       // 2 channels per lane
    int n = blockIdx.x * 4 + (threadIdx.x >> 6);
    if (n >= NN) return;
    int beg = rp[n], end = rp[n + 1];

    v2f acc0 = {0.f, 0.f}, acc1 = {0.f, 0.f};

    for (int chunk = beg; chunk < end; chunk += 64) {
        int l = chunk + lane;
        bool valid = (l < end);
        int   e  = valid ? ssrc[l] : n;        // pad: self row (harmless, ds=0)
        float dv = valid ? dinv[e] : 0.f;
        int cnt = end - chunk;
        if (cnt > 64) cnt = 64;
        for (int jb = 0; jb < cnt; jb += 8) {
#pragma unroll
            for (int j = 0; j < 8; ++j) {
                int s    = __builtin_amdgcn_readlane(e, jb + j);
                float ds = __int_as_float(
                               __builtin_amdgcn_readlane(__float_as_int(dv), jb + j));
                unsigned u = *(const unsigned*)(hw + (size_t)s * HH + c2);
                v2f vv;
                vv.x = __int_as_float((int)(u << 16));
                vv.y = __int_as_float((int)(u & 0xffff0000u));
                v2f d2 = {ds, ds};
                if (j & 1) acc1 += d2 * vv;
                else       acc0 += d2 * vv;
            }
        }
    }
    v2f a = acc0 + acc1;

    // self-loop
    float di = dinv[n];
    {
        unsigned u = *(const unsigned*)(hw + (size_t)n * HH + c2);
        v2f vv;
        vv.x = __int_as_float((int)(u << 16));
        vv.y = __int_as_float((int)(u & 0xffff0000u));
        v2f d2 = {di, di};
        a += d2 * vv;
    }
    a.x *= di;
    a.y *= di;

    float g0 = gamma[c2],   g1 = gamma[c2 + 1];
    float r0 = rv[c2],      r1 = rv[c2 + 1];
    float s0 = g0 * rsqrtf(r0 + EPSV);
    float s1 = g1 * rsqrtf(r1 + EPSV);
    float b0 = fmaf(bsl[c2]     - rm[c2],     s0, beta[c2]);
    float b1 = fmaf(bsl[c2 + 1] - rm[c2 + 1], s1, beta[c2 + 1]);
    float y0 = fmaxf(fmaf(a.x, s0, b0), 0.f);
    float y1 = fmaxf(fmaf(a.y, s1, b1), 0.f);
    ushort2 o;
    o.x = f2bf(y0);
    o.y = f2bf(y1);
    *(ushort2*)(out + (size_t)n * HH + c2) = o;
}

// ---------------- global mean pool (batch sorted, bf16 input) ----------------
__global__ __launch_bounds__(128) void k_pool(const unsigned short* __restrict__ h,
                                              const int* __restrict__ batch,
                                              float* __restrict__ pooled,
                                              float* __restrict__ cnt) {
    int t = threadIdx.x;
    const int chunk = (NN + 1023) / 1024;
    int n0 = blockIdx.x * chunk;
    if (n0 >= NN) return;
    int n1 = n0 + chunk;
    if (n1 > NN) n1 = NN;
    int cur = batch[n0];
    float acc = 0.f;
    int k = 0;
    for (int n = n0; n < n1; ++n) {
        int b = batch[n];
        if (b != cur) {
            atomicAdd(&pooled[(size_t)cur * 128 + t], acc);
            if (t == 0) atomicAdd(&cnt[cur], (float)k);
            acc = 0.f; k = 0; cur = b;
        }
        acc += bf2f(h[(size_t)n * 128 + t]);
        ++k;
    }
    atomicAdd(&pooled[(size_t)cur * 128 + t], acc);
    if (t == 0) atomicAdd(&cnt[cur], (float)k);
}

// ---------------- LSTM (single step, h0=c0=0) + FC ----------------
__global__ __launch_bounds__(128) void k_head(const float* __restrict__ pooled,
                                              const float* __restrict__ cnt,
                                              const float* __restrict__ W_ih,
                                              const float* __restrict__ b_ih,
                                              const float* __restrict__ b_hh,
                                              const float* __restrict__ W_fc,
                                              const float* __restrict__ b_fc,
                                              float* __restrict__ out) {
    __shared__ float pm[128];
    __shared__ float gate[512];
    __shared__ float hn[128];
    int g = blockIdx.x, t = threadIdx.x;
    float cdiv = fmaxf(cnt[g], 1.0f);
    pm[t] = pooled[(size_t)g * 128 + t] / cdiv;
    __syncthreads();
    for (int j = t; j < 512; j += 128) {
        float acc = b_ih[j] + b_hh[j];
        const float* w = W_ih + (size_t)j * 128;
#pragma unroll 8
        for (int k = 0; k < 128; ++k) acc = fmaf(pm[k], w[k], acc);
        gate[j] = acc;
    }
    __syncthreads();
    {
        float gi = gate[t], gg = gate[256 + t], go = gate[384 + t];
        float cc = (1.f / (1.f + expf(-gi))) * tanhf(gg);
        hn[t] = (1.f / (1.f + expf(-go))) * tanhf(cc);
    }
    __syncthreads();
    if (t < 16) {
        float acc = b_fc[t];
        const float* w = W_fc + (size_t)t * 128;
#pragma unroll 8
        for (int k = 0; k < 128; ++k) acc = fmaf(hn[k], w[k], acc);
        out[(size_t)g * 16 + t] = acc;
    }
}

// ---------------- launch ----------------
extern "C" void kernel_launch(void* const* d_in, const int* in_sizes, int n_in,
                              void* d_out, int out_size, void* d_ws, size_t ws_size,
                              hipStream_t stream) {
    const float* x      = (const float*)d_in[0];
    const int*   ei     = (const int*)d_in[1];
    const int*   src    = ei;
    const int*   dst    = ei + EE;
    const int*   batch  = (const int*)d_in[2];
    const float* Ws     = (const float*)d_in[3];
    const float* bs     = (const float*)d_in[4];
    const float* gammas = (const float*)d_in[5];
    const float* betas  = (const float*)d_in[6];
    const float* rms    = (const float*)d_in[7];
    const float* rvs    = (const float*)d_in[8];
    const float* W_ih   = (const float*)d_in[9];
    // d_in[10] = W_hh (unused: h0 = 0)
    const float* b_ih   = (const float*)d_in[11];
    const float* b_hh   = (const float*)d_in[12];
    const float* W_fc   = (const float*)d_in[13];
    const float* b_fc   = (const float*)d_in[14];
    float* out = (float*)d_out;

    char* w = (char*)d_ws;
    unsigned*       gtail  = (unsigned*)(w + OFF_TL);      // 8 L1 tails
    unsigned*       tail2  = gtail + 8;                    // 256 L2 tails
    unsigned*       sbase  = gtail + 8 + 256;              // 256 prefix bases
    float*          dinv   = (float*)(w + OFF_DNV);
    int*            rp     = (int*)(w + OFF_RP);
    int*            ssrc   = (int*)(w + OFF_SRC);
    unsigned*       bins   = (unsigned*)(w + OFF_BIN);
    unsigned*       bins2  = (unsigned*)(w + OFF_B2);
    unsigned short* hwb    = (unsigned short*)(w + OFF_HW);
    unsigned short* h0     = (unsigned short*)(w + OFF_H0);
    float*          pooled = (float*)(w + OFF_PL);
    float*          cntb   = pooled + (size_t)GG * HH;

    hipMemsetAsync(gtail, 0, (8 + 256) * 4, stream);

    k_bin<<<(EE / 4 + 255) / 256, 256, 0, stream>>>(src, dst, bins, gtail);
    k_bin2<<<NSH * NCH, 256, 0, stream>>>(bins, gtail, bins2, tail2);
    k_tailscan<<<1, 256, 0, stream>>>(tail2, sbase, pooled);
    k_hist3<<<256, 256, 0, stream>>>(bins2, tail2, sbase, rp, dinv);
    k_scatter4<<<256, 256, 0, stream>>>(bins2, tail2, rp, ssrc);

    dim3 ggrid((NN + 127) / 128);
    for (int l = 0; l < 3; ++l) {
        if (l == 0)
            gemm_mfma<true><<<ggrid, 256, 0, stream>>>(x, Ws, hwb, NN);
        else
            gemm_mfma<false><<<ggrid, 256, 0, stream>>>(h0, Ws + (size_t)l * 128 * 128, hwb, NN);
        k_agg<<<(NN + 3) / 4, 256, 0, stream>>>(hwb, rp, ssrc, dinv,
                                                bs + l * 128, gammas + l * 128, betas + l * 128,
                                                rms + l * 128, rvs + l * 128, h0);
    }
    k_pool<<<1024, 128, 0, stream>>>(h0, batch, pooled, cntb);
    k_head<<<GG, 128, 0, stream>>>(pooled, cntb, W_ih, b_ih, b_hh, W_fc, b_fc, out);
}

// Round 10
// 443.174 us; speedup vs baseline: 2.1158x; 1.0729x over previous
//
#include <hip/hip_runtime.h>
#include <math.h>

// ---------------- problem constants ----------------
constexpr int   NN  = 100000;    // nodes
constexpr int   EE  = 1600000;   // edges
constexpr int   HH  = 128;       // hidden / in_channels
constexpr int   GG  = 128;       // graphs
constexpr float EPSV = 1e-5f;
constexpr int   NSB = 256;                     // global sub-bins
constexpr int   SUBW = (NN + NSB - 1) / NSB;   // 391 nodes per sub-bin
constexpr int   CAP2 = 8192;                   // per-sub-bin capacity (avg 6250, +24 sigma)
constexpr int   GEMM_BLOCKS = (NN + 127) / 128;  // 782

typedef __attribute__((ext_vector_type(8))) short  short8;
typedef __attribute__((ext_vector_type(4))) float  f32x4;
typedef __attribute__((ext_vector_type(2))) float  v2f;

__device__ __forceinline__ unsigned short f2bf(float f) {
    union { float f; unsigned u; } v; v.f = f;
    unsigned r = v.u + 0x7FFF + ((v.u >> 16) & 1);   // round-to-nearest-even
    return (unsigned short)(r >> 16);
}
__device__ __forceinline__ float bf2f(unsigned short b) {
    union { unsigned u; float f; } v; v.u = ((unsigned)b) << 16;
    return v.f;
}

// ---------------- workspace layout ----------------
constexpr size_t A256(size_t x) { return (x + 255) & ~(size_t)255; }
constexpr size_t OFF_TL  = 0;                                       // tail2[256]
constexpr size_t OFF_DNV = A256(OFF_TL  + 256 * 4);                 // N floats dinv
constexpr size_t OFF_RP  = A256(OFF_DNV + (size_t)NN * 4);          // (N+1) ints
constexpr size_t OFF_SRC = A256(OFF_RP  + (size_t)(NN + 1) * 4);    // E ints sorted src
constexpr size_t OFF_B2  = A256(OFF_SRC + (size_t)EE * 4);          // 256*CAP2 uints sub-bins
constexpr size_t OFF_HW  = A256(OFF_B2  + (size_t)NSB * CAP2 * 4);  // N*H bf16 (h@W)
constexpr size_t OFF_H0  = A256(OFF_HW  + (size_t)NN * HH * 2);     // N*H bf16 (h)
constexpr size_t OFF_PL  = A256(OFF_H0  + (size_t)NN * HH * 2);     // G*H f32 pooled + G f32 cnt

// ---------------- GEMM body: C[N,128] = A[N,128] @ W[128,128], MFMA bf16, split-W ----------------
// A fragments preloaded once; two 64-col W-stage phases; FP32A reads fp32 x directly.
template<bool FP32A>
__device__ __forceinline__ void gemm_body(const void* __restrict__ Ap,
                                          const float* __restrict__ W,
                                          unsigned short* __restrict__ C,
                                          int nrows, int rb) {
    __shared__ unsigned short WtH[64 * 136];  // reused as Cs[128][68] in epilogue
    __shared__ unsigned short WtL[64 * 136];
    int t = threadIdx.x;
    int row0 = rb * 128;
    int wv = t >> 6, lane = t & 63, m = lane & 15, q = lane >> 4;
    long rowA = row0 + wv * 32 + m;
    long rowB = rowA + 16;

    short8 a[2][4];
#pragma unroll
    for (int kc = 0; kc < 4; ++kc) {
        int ko = kc * 32 + q * 8;
        if (FP32A) {
            const float* Af = (const float*)Ap;
            float4 f0 = {0,0,0,0}, f1 = {0,0,0,0}, g0 = {0,0,0,0}, g1 = {0,0,0,0};
            if (rowA < nrows) {
                f0 = *(const float4*)(Af + rowA * 128 + ko);
                f1 = *(const float4*)(Af + rowA * 128 + ko + 4);
            }
            if (rowB < nrows) {
                g0 = *(const float4*)(Af + rowB * 128 + ko);
                g1 = *(const float4*)(Af + rowB * 128 + ko + 4);
            }
            union { short8 s; unsigned short u[8]; } ua, ub;
            ua.u[0] = f2bf(f0.x); ua.u[1] = f2bf(f0.y); ua.u[2] = f2bf(f0.z); ua.u[3] = f2bf(f0.w);
            ua.u[4] = f2bf(f1.x); ua.u[5] = f2bf(f1.y); ua.u[6] = f2bf(f1.z); ua.u[7] = f2bf(f1.w);
            ub.u[0] = f2bf(g0.x); ub.u[1] = f2bf(g0.y); ub.u[2] = f2bf(g0.z); ub.u[3] = f2bf(g0.w);
            ub.u[4] = f2bf(g1.x); ub.u[5] = f2bf(g1.y); ub.u[6] = f2bf(g1.z); ub.u[7] = f2bf(g1.w);
            a[0][kc] = ua.s; a[1][kc] = ub.s;
        } else {
            const unsigned short* Ab = (const unsigned short*)Ap;
            short8 z = {};
            a[0][kc] = (rowA < nrows) ? *(const short8*)(Ab + rowA * 128 + ko) : z;
            a[1][kc] = (rowB < nrows) ? *(const short8*)(Ab + rowB * 128 + ko) : z;
        }
    }

    for (int half = 0; half < 2; ++half) {
        int c0 = half * 64;
        __syncthreads();
        for (int idx = t; idx < 64 * 128; idx += 256) {
            int k = idx >> 6, c = idx & 63;
            float w = W[k * 128 + c0 + c];
            unsigned short hb = f2bf(w);
            WtH[c * 136 + k] = hb;
            WtL[c * 136 + k] = f2bf(w - bf2f(hb));
        }
        __syncthreads();
        f32x4 acc[2][4] = {};
#pragma unroll
        for (int kc = 0; kc < 4; ++kc) {
            int ko = kc * 32 + q * 8;
#pragma unroll
            for (int ct = 0; ct < 4; ++ct) {
                short8 bh = *(const short8*)(WtH + (ct * 16 + m) * 136 + ko);
                short8 bl = *(const short8*)(WtL + (ct * 16 + m) * 136 + ko);
                acc[0][ct] = __builtin_amdgcn_mfma_f32_16x16x32_bf16(a[0][kc], bh, acc[0][ct], 0, 0, 0);
                acc[0][ct] = __builtin_amdgcn_mfma_f32_16x16x32_bf16(a[0][kc], bl, acc[0][ct], 0, 0, 0);
                acc[1][ct] = __builtin_amdgcn_mfma_f32_16x16x32_bf16(a[1][kc], bh, acc[1][ct], 0, 0, 0);
                acc[1][ct] = __builtin_amdgcn_mfma_f32_16x16x32_bf16(a[1][kc], bl, acc[1][ct], 0, 0, 0);
            }
        }
        __syncthreads();
        unsigned short* Cs = WtH;  // [128][68]
#pragma unroll
        for (int rt = 0; rt < 2; ++rt)
#pragma unroll
            for (int ct = 0; ct < 4; ++ct)
#pragma unroll
                for (int r = 0; r < 4; ++r) {
                    int rl = wv * 32 + rt * 16 + q * 4 + r;
                    Cs[rl * 68 + ct * 16 + m] = f2bf(acc[rt][ct][r]);
                }
        __syncthreads();
        for (int idx = t; idx < 128 * 16; idx += 256) {
            int row = idx >> 4, ch = idx & 15;
            long grow = row0 + row;
            if (grow < nrows)
                *(ushort4*)(C + grow * 128 + c0 + ch * 4) = *(const ushort4*)(Cs + row * 68 + ch * 4);
        }
    }
}

// ---------------- direct binning: edges -> 256 global sub-bins, 1 kernel ----------------
// R9 lesson: k_bin's 1.6M LDS atomics over 8 counters serialize heavily; two
// binning passes + 5-kernel CSR chain cost ~dozens of us in work+gaps. Here:
// each block two-passes its OWN ~6.2k-edge chunk (L2-hot 2nd pass), counts over
// 256 LDS counters (low contention), reserves global space, writes packed
// (dlocal<<17|src) straight to its per-sub-bin runs.
__device__ void binall_body(const int* __restrict__ src, const int* __restrict__ dst,
                            unsigned* __restrict__ bins2, unsigned* __restrict__ tail2,
                            int b) {
    __shared__ unsigned cnt[NSB];
    __shared__ unsigned cur[NSB];
    int t = threadIdx.x;
    cnt[t] = 0;
    __syncthreads();
    const int nvec = EE / 4;                 // 400000
    int csz = (nvec + NSB - 1) / NSB;        // 1563
    int i0 = b * csz;
    int i1 = i0 + csz; if (i1 > nvec) i1 = nvec;
    const int4* d4 = (const int4*)dst;
    const int4* s4 = (const int4*)src;
    for (int i = i0 + t; i < i1; i += 256) {
        int4 d = d4[i];
        atomicAdd(&cnt[(unsigned)d.x / SUBW], 1u);
        atomicAdd(&cnt[(unsigned)d.y / SUBW], 1u);
        atomicAdd(&cnt[(unsigned)d.z / SUBW], 1u);
        atomicAdd(&cnt[(unsigned)d.w / SUBW], 1u);
    }
    __syncthreads();
    cur[t] = atomicAdd(&tail2[t], cnt[t]);   // base within sub-bin region
    __syncthreads();
    for (int i = i0 + t; i < i1; i += 256) {
        int4 d = d4[i];
        int4 s = s4[i];
        int dd[4] = {d.x, d.y, d.z, d.w};
        int ss[4] = {s.x, s.y, s.z, s.w};
#pragma unroll
        for (int c = 0; c < 4; ++c) {
            unsigned gsb = (unsigned)dd[c] / SUBW;
            unsigned p = atomicAdd(&cur[gsb], 1u);
            if (p < (unsigned)CAP2)
                bins2[(size_t)gsb * CAP2 + p] =
                    ((unsigned)(dd[c] - gsb * SUBW) << 17) | (unsigned)ss[c];
        }
    }
}

// ---------------- K1: gemm layer 0 (fp32 A) || binall, block-range split ----------------
__global__ __launch_bounds__(256) void k_gemm0_bin(const float* __restrict__ x,
                                                   const float* __restrict__ W,
                                                   unsigned short* __restrict__ C,
                                                   const int* __restrict__ src,
                                                   const int* __restrict__ dst,
                                                   unsigned* __restrict__ bins2,
                                                   unsigned* __restrict__ tail2) {
    if (blockIdx.x < GEMM_BLOCKS)
        gemm_body<true>(x, W, C, NN, blockIdx.x);
    else
        binall_body(src, dst, bins2, tail2, blockIdx.x - GEMM_BLOCKS);
}

__global__ __launch_bounds__(256) void k_gemm(const unsigned short* __restrict__ A,
                                              const float* __restrict__ W,
                                              unsigned short* __restrict__ C) {
    gemm_body<false>(A, W, C, NN, blockIdx.x);
}

// ---------------- k_build: tail-prefix + hist + scan -> rp,dinv + scatter, fused ----------------
__global__ __launch_bounds__(256) void k_build(const unsigned* __restrict__ bins2,
                                               const unsigned* __restrict__ tail2,
                                               int* __restrict__ rp,
                                               float* __restrict__ dinv,
                                               int* __restrict__ ssrc,
                                               float* __restrict__ pooled) {
    __shared__ int hist[SUBW];           // hist -> cursors
    __shared__ int sa[512], sd[512];
    __shared__ unsigned ta[256], tb[256];
    int b = blockIdx.x, t = threadIdx.x;

    // zero pooled (16512 floats spread over blocks 0..64)
    if (b < 65) {
        int idx = b * 256 + t;
        if (idx < GG * HH + GG) pooled[idx] = 0.f;
    }

    // inline prefix over tail2 (replaces separate k_tailscan kernel)
    unsigned v = tail2[t];
    ta[t] = v;
    __syncthreads();
    unsigned *sp = ta, *dp = tb;
    for (int off = 1; off < 256; off <<= 1) {
        dp[t] = sp[t] + ((t >= off) ? sp[t - off] : 0u);
        __syncthreads();
        unsigned* tmp = sp; sp = dp; dp = tmp;
    }
    unsigned base = sp[b] - tail2[b];    // exclusive prefix for this sub-bin
    unsigned m = tail2[b];
    if (m > (unsigned)CAP2) m = CAP2;

    int lo = b * SUBW;
    int nn = NN - lo; if (nn > SUBW) nn = SUBW;
    for (int i = t; i < nn; i += 256) hist[i] = 0;
    __syncthreads();

    const unsigned* bb = bins2 + (size_t)b * CAP2;
    unsigned nv = m >> 2;
    for (unsigned i = t; i < nv; i += 256) {
        uint4 u = ((const uint4*)bb)[i];
        atomicAdd(&hist[u.x >> 17], 1);
        atomicAdd(&hist[u.y >> 17], 1);
        atomicAdd(&hist[u.z >> 17], 1);
        atomicAdd(&hist[u.w >> 17], 1);
    }
    for (unsigned i = (m & ~3u) + t; i < m; i += 256)
        atomicAdd(&hist[bb[i] >> 17], 1);
    __syncthreads();

    // inclusive Hillis-Steele over 512 (padded), 2 elems/thread
    sa[t]       = (t < nn)       ? hist[t]       : 0;
    sa[t + 256] = (t + 256 < nn) ? hist[t + 256] : 0;
    __syncthreads();
    int* s = sa; int* d = sd;
    for (int off = 1; off < 512; off <<= 1) {
        d[t]       = s[t]       + ((t >= off)       ? s[t - off]       : 0);
        d[t + 256] = s[t + 256] + ((t + 256 >= off) ? s[t + 256 - off] : 0);
        __syncthreads();
        int* tmp = s; s = d; d = tmp;
    }

    // rp + dinv; keep cursors in LDS (reuse hist)
    for (int i = t; i < nn; i += 256) {
        int cur0 = (int)base + (i ? s[i - 1] : 0);
        rp[lo + i]   = cur0;
        dinv[lo + i] = rsqrtf((float)(hist[i] + 1));  // +1 self-loop
        // note: hist[i] still holds degree; overwrite AFTER dinv computed
    }
    __syncthreads();
    for (int i = t; i < nn; i += 256)
        hist[i] = (int)base + (i ? s[i - 1] : 0);
    if (b == 255 && t == 0) rp[NN] = EE;
    __syncthreads();

    // scatter: exclusive ssrc region, LDS cursor atomics
    for (unsigned i = t; i < nv; i += 256) {
        uint4 u = ((const uint4*)bb)[i];
        int p;
        p = atomicAdd(&hist[u.x >> 17], 1); ssrc[p] = (int)(u.x & 0x1FFFFu);
        p = atomicAdd(&hist[u.y >> 17], 1); ssrc[p] = (int)(u.y & 0x1FFFFu);
        p = atomicAdd(&hist[u.z >> 17], 1); ssrc[p] = (int)(u.z & 0x1FFFFu);
        p = atomicAdd(&hist[u.w >> 17], 1); ssrc[p] = (int)(u.w & 0x1FFFFu);
    }
    for (unsigned i = (m & ~3u) + t; i < m; i += 256) {
        unsigned u = bb[i];
        int p = atomicAdd(&hist[u >> 17], 1);
        ssrc[p] = (int)(u & 0x1FFFFu);
    }
}

// ---------------- aggregate + bias + BN + ReLU ----------------
// one edge per FULL wave; 64-edge metadata preload; readlane -> SGPR row base;
// 2 ch/lane packed float2 FMA; pad = self row with ds=0.
__global__ __launch_bounds__(256) void k_agg(const unsigned short* __restrict__ hw,
                                             const int* __restrict__ rp,
                                             const int* __restrict__ ssrc,
                                             const float* __restrict__ dinv,
                                             const float* __restrict__ bsl,
                                             const float* __restrict__ gamma,
                                             const float* __restrict__ beta,
                                             const float* __restrict__ rm,
                                             const float* __restrict__ rv,
                                             unsigned short* __restrict__ out) {
    int lane = threadIdx.x & 63;
    int c2   = lane * 2;                       // 2 channels per lane
    int n = blockIdx.x * 4 + (threadIdx.x >> 6);
    if (n >= NN) return;
    int beg = rp[n], end = rp[n + 1];

    v2f acc0 = {0.f, 0.f}, acc1 = {0.f, 0.f};

    for (int chunk = beg; chunk < end; chunk += 64) {
        int l = chunk + lane;
        bool valid = (l < end);
        int   e  = valid ? ssrc[l] : n;        // pad: self row (harmless, ds=0)
        float dv = valid ? dinv[e] : 0.f;
        int cnt = end - chunk;
        if (cnt > 64) cnt = 64;
        for (int jb = 0; jb < cnt; jb += 8) {
#pragma unroll
            for (int j = 0; j < 8; ++j) {
                int s    = __builtin_amdgcn_readlane(e, jb + j);
                float ds = __int_as_float(
                               __builtin_amdgcn_readlane(__float_as_int(dv), jb + j));
                unsigned u = *(const unsigned*)(hw + (size_t)s * HH + c2);
                v2f vv;
                vv.x = __int_as_float((int)(u << 16));
                vv.y = __int_as_float((int)(u & 0xffff0000u));
                v2f d2 = {ds, ds};
                if (j & 1) acc1 += d2 * vv;
                else       acc0 += d2 * vv;
            }
        }
    }
    v2f a = acc0 + acc1;

    // self-loop
    float di = dinv[n];
    {
        unsigned u = *(const unsigned*)(hw + (size_t)n * HH + c2);
        v2f vv;
        vv.x = __int_as_float((int)(u << 16));
        vv.y = __int_as_float((int)(u & 0xffff0000u));
        v2f d2 = {di, di};
        a += d2 * vv;
    }
    a.x *= di;
    a.y *= di;

    float g0 = gamma[c2],   g1 = gamma[c2 + 1];
    float r0 = rv[c2],      r1 = rv[c2 + 1];
    float s0 = g0 * rsqrtf(r0 + EPSV);
    float s1 = g1 * rsqrtf(r1 + EPSV);
    float b0 = fmaf(bsl[c2]     - rm[c2],     s0, beta[c2]);
    float b1 = fmaf(bsl[c2 + 1] - rm[c2 + 1], s1, beta[c2 + 1]);
    float y0 = fmaxf(fmaf(a.x, s0, b0), 0.f);
    float y1 = fmaxf(fmaf(a.y, s1, b1), 0.f);
    ushort2 o;
    o.x = f2bf(y0);
    o.y = f2bf(y1);
    *(ushort2*)(out + (size_t)n * HH + c2) = o;
}

// ---------------- global mean pool (batch sorted, bf16 input) ----------------
__global__ __launch_bounds__(128) void k_pool(const unsigned short* __restrict__ h,
                                              const int* __restrict__ batch,
                                              float* __restrict__ pooled,
                                              float* __restrict__ cnt) {
    int t = threadIdx.x;
    const int chunk = (NN + 1023) / 1024;
    int n0 = blockIdx.x * chunk;
    if (n0 >= NN) return;
    int n1 = n0 + chunk;
    if (n1 > NN) n1 = NN;
    int cur = batch[n0];
    float acc = 0.f;
    int k = 0;
    for (int n = n0; n < n1; ++n) {
        int b = batch[n];
        if (b != cur) {
            atomicAdd(&pooled[(size_t)cur * 128 + t], acc);
            if (t == 0) atomicAdd(&cnt[cur], (float)k);
            acc = 0.f; k = 0; cur = b;
        }
        acc += bf2f(h[(size_t)n * 128 + t]);
        ++k;
    }
    atomicAdd(&pooled[(size_t)cur * 128 + t], acc);
    if (t == 0) atomicAdd(&cnt[cur], (float)k);
}

// ---------------- LSTM (single step, h0=c0=0) + FC ----------------
__global__ __launch_bounds__(128) void k_head(const float* __restrict__ pooled,
                                              const float* __restrict__ cnt,
                                              const float* __restrict__ W_ih,
                                              const float* __restrict__ b_ih,
                                              const float* __restrict__ b_hh,
                                              const float* __restrict__ W_fc,
                                              const float* __restrict__ b_fc,
                                              float* __restrict__ out) {
    __shared__ float pm[128];
    __shared__ float gate[512];
    __shared__ float hn[128];
    int g = blockIdx.x, t = threadIdx.x;
    float cdiv = fmaxf(cnt[g], 1.0f);
    pm[t] = pooled[(size_t)g * 128 + t] / cdiv;
    __syncthreads();
    for (int j = t; j < 512; j += 128) {
        float acc = b_ih[j] + b_hh[j];
        const float* w = W_ih + (size_t)j * 128;
#pragma unroll 8
        for (int k = 0; k < 128; ++k) acc = fmaf(pm[k], w[k], acc);
        gate[j] = acc;
    }
    __syncthreads();
    {
        float gi = gate[t], gg = gate[256 + t], go = gate[384 + t];
        float cc = (1.f / (1.f + expf(-gi))) * tanhf(gg);
        hn[t] = (1.f / (1.f + expf(-go))) * tanhf(cc);
    }
    __syncthreads();
    if (t < 16) {
        float acc = b_fc[t];
        const float* w = W_fc + (size_t)t * 128;
#pragma unroll 8
        for (int k = 0; k < 128; ++k) acc = fmaf(hn[k], w[k], acc);
        out[(size_t)g * 16 + t] = acc;
    }
}

// ---------------- launch ----------------
extern "C" void kernel_launch(void* const* d_in, const int* in_sizes, int n_in,
                              void* d_out, int out_size, void* d_ws, size_t ws_size,
                              hipStream_t stream) {
    const float* x      = (const float*)d_in[0];
    const int*   ei     = (const int*)d_in[1];
    const int*   src    = ei;
    const int*   dst    = ei + EE;
    const int*   batch  = (const int*)d_in[2];
    const float* Ws     = (const float*)d_in[3];
    const float* bs     = (const float*)d_in[4];
    const float* gammas = (const float*)d_in[5];
    const float* betas  = (const float*)d_in[6];
    const float* rms    = (const float*)d_in[7];
    const float* rvs    = (const float*)d_in[8];
    const float* W_ih   = (const float*)d_in[9];
    // d_in[10] = W_hh (unused: h0 = 0)
    const float* b_ih   = (const float*)d_in[11];
    const float* b_hh   = (const float*)d_in[12];
    const float* W_fc   = (const float*)d_in[13];
    const float* b_fc   = (const float*)d_in[14];
    float* out = (float*)d_out;

    char* w = (char*)d_ws;
    unsigned*       tail2  = (unsigned*)(w + OFF_TL);
    float*          dinv   = (float*)(w + OFF_DNV);
    int*            rp     = (int*)(w + OFF_RP);
    int*            ssrc   = (int*)(w + OFF_SRC);
    unsigned*       bins2  = (unsigned*)(w + OFF_B2);
    unsigned short* hwb    = (unsigned short*)(w + OFF_HW);
    unsigned short* h0     = (unsigned short*)(w + OFF_H0);
    float*          pooled = (float*)(w + OFF_PL);
    float*          cntb   = pooled + (size_t)GG * HH;

    hipMemsetAsync(tail2, 0, 256 * 4, stream);

    // K1: layer-0 GEMM and edge binning overlapped in one launch
    k_gemm0_bin<<<GEMM_BLOCKS + NSB, 256, 0, stream>>>(x, Ws, hwb, src, dst, bins2, tail2);
    // K2: CSR build fully fused (tail prefix + hist + scan + rp/dinv + scatter)
    k_build<<<NSB, 256, 0, stream>>>(bins2, tail2, rp, dinv, ssrc, pooled);

    for (int l = 0; l < 3; ++l) {
        if (l > 0)
            k_gemm<<<GEMM_BLOCKS, 256, 0, stream>>>(h0, Ws + (size_t)l * 128 * 128, hwb);
        k_agg<<<(NN + 3) / 4, 256, 0, stream>>>(hwb, rp, ssrc, dinv,
                                                bs + l * 128, gammas + l * 128, betas + l * 128,
                                                rms + l * 128, rvs + l * 128, h0);
    }
    k_pool<<<1024, 128, 0, stream>>>(h0, batch, pooled, cntb);
    k_head<<<GG, 128, 0, stream>>>(pooled, cntb, W_ih, b_ih, b_hh, W_fc, b_fc, out);
}